// Round 9
// baseline (854.401 us; speedup 1.0000x reference)
//
#include <hip/hip_runtime.h>
#include <hip/hip_bf16.h>
#include <math.h>

#define NROW   8192      // B*H*W z-rows
#define KCODE  8192      // codebook entries
#define CD     256
#define HWSZ   1024
#define NBLK   32        // 256-code blocks for top-3 candidates
#define MARGIN 7.5e-5f

#define QOFF   ((size_t)NROW * CD)   // 2097152: loss at QOFF, indices at QOFF+1

typedef __attribute__((ext_vector_type(8))) short short8;
typedef __attribute__((ext_vector_type(4))) float f32x4;
typedef unsigned long long u64;

// sortable key: high32 = monotone float map, low32 = code (lex tie -> low index)
__device__ __forceinline__ u64 makeKey(float v, int code) {
  unsigned u = __float_as_uint(v);
  unsigned m = (u & 0x80000000u) ? ~u : (u | 0x80000000u);
  return ((u64)m << 32) | (unsigned)code;
}
__device__ __forceinline__ float keyVal(u64 k) {
  unsigned m = (unsigned)(k >> 32);
  unsigned u = (m & 0x80000000u) ? (m ^ 0x80000000u) : ~m;
  return __uint_as_float(u);
}
__device__ __forceinline__ void ins3(u64 k, u64& t1, u64& t2, u64& t3) {
  if (k < t1) { t3 = t2; t2 = t1; t1 = k; }
  else if (k < t2) { t3 = t2; t2 = k; }
  else if (k < t3) { t3 = k; }
}

// ---------------- k1: exact-numpy x2 per row (R2-proven block, minus bf16 out) --------
__global__ __launch_bounds__(256) void x2_kernel(
    const float* __restrict__ z, float* __restrict__ x2g) {
  __shared__ float xs[32 * 260];
  int tid = threadIdx.x;
  int n0 = blockIdx.x * 32;
  int b = n0 >> 10;
  int hw0 = n0 & 1023;
  const float* zb = z + (size_t)b * (CD * HWSZ) + hw0;
  {
    int r = tid & 31;
    int cbase = tid >> 5;
    for (int it = 0; it < 32; ++it) {
      int c = cbase + it * 8;
      xs[r * 260 + c] = zb[(size_t)c * HWSZ + r];
    }
  }
  __syncthreads();
  if (tid < 32) {
#pragma clang fp contract(off)
    const float* xr = &xs[tid * 260];
    float r0[8], r1[8];
#pragma unroll
    for (int j = 0; j < 8; ++j) {
      float v = xr[j];       r0[j] = v * v;
      float w = xr[128 + j]; r1[j] = w * w;
    }
    for (int i = 8; i < 128; i += 8) {
#pragma unroll
      for (int j = 0; j < 8; ++j) {
        float v = xr[i + j];       float a  = v * v; r0[j] = r0[j] + a;
        float w = xr[128 + i + j]; float b2 = w * w; r1[j] = r1[j] + b2;
      }
    }
    float lo = ((r0[0] + r0[1]) + (r0[2] + r0[3])) + ((r0[4] + r0[5]) + (r0[6] + r0[7]));
    float hi = ((r1[0] + r1[1]) + (r1[2] + r1[3])) + ((r1[4] + r1[5]) + (r1[6] + r1[7]));
    x2g[n0 + tid] = lo + hi;
  }
}

// ---------------- k2: fp32 VALU GEMM + per-(row, 256-code-block) top-3 ----------------
// Built on R2's VALIDATED pipe models. Tile: 256 codes x 128 rows, K-chunk 32.
// Thread (cg=tid&15, rg=tid>>4): 16 codes x 8 rows microtile, 128 acc regs.
// LDS: x[k][row] (132-float rows), e[k][16 slabs x 80B] (slab skew -> <=2-way reads).
// Reads ONLY d_in. No MFMA. 6 ds_read_b128 per 128 FMAs -> VALU/LDS ~balanced.
__global__ __launch_bounds__(256, 2) void gemm_valu_top3_kernel(
    const float* __restrict__ z, const float* __restrict__ emb,
    u64* __restrict__ pK1, u64* __restrict__ pK2, u64* __restrict__ pK3) {
  __shared__ __align__(16) char SM[57856];   // x: [0,16896), e: [16896, 57856)
  int tid = threadIdx.x;
  int bid = blockIdx.x;            // 0..2047
  int cbx = bid & 31;              // code tile 0..31
  int rby = bid >> 5;              // row tile 0..63
  int cb0 = cbx * 256;
  int rb0 = rby * 128;
  int cg = tid & 15;               // code group: codes cg*16..+15
  int rgf = tid >> 4;              // row group: rows rgf*8..+7

  int b = rb0 >> 10;
  int hw0 = rb0 & 1023;
  const float* zb = z + (size_t)b * (CD * HWSZ) + hw0;

  float acc[128];
#pragma unroll
  for (int i = 0; i < 128; ++i) acc[i] = 0.f;

  for (int kc = 0; kc < 8; ++kc) {
    int k0 = kc * 32;
    // global loads (issued before barrier; latency overlaps other waves' compute)
    float xv[16];
    {
      const float* src = zb + (size_t)(k0 + (tid >> 3)) * HWSZ + (tid & 7) * 16;
      *(float4*)&xv[0]  = *(const float4*)(src);
      *(float4*)&xv[4]  = *(const float4*)(src + 4);
      *(float4*)&xv[8]  = *(const float4*)(src + 8);
      *(float4*)&xv[12] = *(const float4*)(src + 12);
    }
    float ev[32];
    {
      const float* src = emb + (size_t)(cb0 + tid) * CD + k0;
#pragma unroll
      for (int m = 0; m < 8; ++m)
        *(float4*)&ev[m * 4] = *(const float4*)(src + m * 4);
    }
    __syncthreads();   // previous chunk's LDS reads complete
    { // x write: [c_local=tid>>3][hw-block=(tid&7)*16]  (<=2-way)
      char* xw = SM + (tid >> 3) * 528 + (tid & 7) * 64;
      *(float4*)(xw)      = *(float4*)&xv[0];
      *(float4*)(xw + 16) = *(float4*)&xv[4];
      *(float4*)(xw + 32) = *(float4*)&xv[8];
      *(float4*)(xw + 48) = *(float4*)&xv[12];
    }
    { // e write (transposed): code tid -> slab tid>>4, pos tid&15
      char* eb = SM + 16896 + (tid >> 4) * 80 + (tid & 15) * 4;
#pragma unroll
      for (int kk = 0; kk < 32; ++kk)
        *(float*)(eb + kk * 1280) = ev[kk];
    }
    __syncthreads();   // tile ready

    for (int k = 0; k < 32; ++k) {
      float a8[8], b16[16];
      {
        const char* xr = SM + k * 528 + rgf * 32;
        *(float4*)&a8[0] = *(const float4*)(xr);
        *(float4*)&a8[4] = *(const float4*)(xr + 16);
      }
      {
        const char* er = SM + 16896 + k * 1280 + cg * 80;
#pragma unroll
        for (int q = 0; q < 4; ++q)
          *(float4*)&b16[q * 4] = *(const float4*)(er + q * 16);
      }
#pragma unroll
      for (int ii = 0; ii < 8; ++ii)
#pragma unroll
        for (int jj = 0; jj < 16; ++jj)
          acc[ii * 16 + jj] = fmaf(a8[ii], b16[jj], acc[ii * 16 + jj]);
    }
  }

  // epilogue: per-thread top-3 per row over its 16 codes, then 16-way LDS merge
  __syncthreads();                 // tiles dead; overlay redK
  u64* redK = (u64*)SM;            // [128 rows][16 cg][3] = 48 KB
#pragma unroll
  for (int ii = 0; ii < 8; ++ii) {
    u64 t1 = ~0ull, t2 = ~0ull, t3 = ~0ull;
#pragma unroll
    for (int jj = 0; jj < 16; ++jj) {
      float v = -2.0f * acc[ii * 16 + jj];   // x2 cancels per-row; monotone
      ins3(makeKey(v, cb0 + cg * 16 + jj), t1, t2, t3);
    }
    int row = rgf * 8 + ii;
    redK[(row * 16 + cg) * 3 + 0] = t1;
    redK[(row * 16 + cg) * 3 + 1] = t2;
    redK[(row * 16 + cg) * 3 + 2] = t3;
  }
  __syncthreads();
  if (tid < 128) {
    u64 t1 = ~0ull, t2 = ~0ull, t3 = ~0ull;
    for (int g = 0; g < 16; ++g) {
      ins3(redK[(tid * 16 + g) * 3 + 0], t1, t2, t3);
      ins3(redK[(tid * 16 + g) * 3 + 1], t1, t2, t3);
      ins3(redK[(tid * 16 + g) * 3 + 2], t1, t2, t3);
    }
    size_t o = (size_t)cbx * NROW + rb0 + tid;
    pK1[o] = t1; pK2[o] = t2; pK3[o] = t3;
  }
}

// ---------------- k3: merge blocks + exact re-rank (R2 semantics, validated) ----------
__global__ __launch_bounds__(256) void merge_rerank_kernel(
    const float* __restrict__ z, const float* __restrict__ emb,
    const u64* __restrict__ pK1, const u64* __restrict__ pK2,
    const u64* __restrict__ pK3, const float* __restrict__ x2g,
    int* __restrict__ idx, float* __restrict__ out) {
  int n = blockIdx.x * 256 + threadIdx.x;
  u64 kmin = ~0ull;
  for (int blk = 0; blk < NBLK; ++blk) {
    u64 k = pK1[(size_t)blk * NROW + n];
    if (k < kmin) kmin = k;
  }
  float vcut = keyVal(kmin) + MARGIN;
  int cand[8]; int nc = 0;
  for (int blk = 0; blk < NBLK; ++blk) {
    size_t o = (size_t)blk * NROW + n;
    u64 k1 = pK1[o], k2 = pK2[o], k3 = pK3[o];
    if (keyVal(k1) <= vcut && nc < 8) cand[nc++] = (int)(k1 & 0xffffffffu);
    if (keyVal(k2) <= vcut && nc < 8) cand[nc++] = (int)(k2 & 0xffffffffu);
    if (keyVal(k3) <= vcut && nc < 8) cand[nc++] = (int)(k3 & 0xffffffffu);
  }
  int b = n >> 10, hw = n & 1023;
  const float* zp = z + (size_t)b * (CD * HWSZ) + hw;
  float x2 = x2g[n];
  float bs = INFINITY; int bi = 0x7fffffff;
  for (int c0 = 0; c0 < nc; ++c0) {
    int k = cand[c0];
    const float* ep = emb + (size_t)k * CD;
    float acc = 0.f;
    for (int c = 0; c < CD; ++c)                 // sequential fmaf chain == R2 dot
      acc = fmaf(zp[(size_t)c * HWSZ], ep[c], acc);
    float s = fmaf(-2.f, acc, x2);               // single rounding == np grid
    if (s < bs || (s == bs && k < bi)) { bs = s; bi = k; }
  }
  idx[n] = bi;
  out[QOFF + 1 + n] = (float)bi;
}

// ---------------- k4: gather quantized + loss partials (R2-proven) ----------------
__global__ __launch_bounds__(256) void gather_kernel(
    const float* __restrict__ z, const float* __restrict__ emb,
    const int* __restrict__ idx, float* __restrict__ out,
    float* __restrict__ lossPart) {
  __shared__ int sidx[64];
  __shared__ float swsum[4];
  int tid = threadIdx.x;
  int bid = blockIdx.x;
  int n0 = bid * 64;
  if (tid < 64) sidx[tid] = idx[n0 + tid];
  __syncthreads();
  int lane = tid & 63;
  int cw = tid >> 6;
  int b = n0 >> 10;
  int hw = (n0 & 1023) + lane;
  const float* erow = emb + (size_t)sidx[lane] * CD;
  float lacc = 0.f;
  for (int ci = 0; ci < 64; ++ci) {
    int c = cw * 64 + ci;
    float q = erow[c];
    size_t o = (size_t)b * (CD * HWSZ) + (size_t)c * HWSZ + hw;
    float zv = z[o];
    out[o] = q;
    float d = q - zv;
    lacc += d * d;
  }
#pragma unroll
  for (int off = 32; off > 0; off >>= 1) lacc += __shfl_down(lacc, off, 64);
  if (lane == 0) swsum[cw] = lacc;
  __syncthreads();
  if (tid == 0) lossPart[bid] = swsum[0] + swsum[1] + swsum[2] + swsum[3];
}

__global__ void loss_kernel(const float* __restrict__ lossPart, float* __restrict__ out) {
  if (threadIdx.x == 0) {
    double s = 0.0;
    for (int i = 0; i < 128; ++i) s += (double)lossPart[i];
    out[QOFF] = (float)(s * 1.25 / (double)(NROW * CD));
  }
}

// ================= DIAGNOSTIC PROBES (read-only, asm-kept-alive) =================
#define PSTEP(a, b) { _Pragma("unroll") for (int i = 0; i < 4; ++i) \
    _Pragma("unroll") for (int j = 0; j < 8; ++j) \
      acc[i][j] = __builtin_amdgcn_mfma_f32_16x16x32_bf16(a[i], b[j], acc[i][j], 0, 0, 0); }

// Probe A: pure MFMA (no loads). 256 MFMA/wave, R7 density.
__global__ __launch_bounds__(256, 2) void probe_mfma_only() {
  int lane = threadIdx.x & 63;
  short8 a[4], b[8];
#pragma unroll
  for (int i = 0; i < 4; ++i) {
    short8 t;
#pragma unroll
    for (int j = 0; j < 8; ++j) t[j] = (short)(lane * 3 + i + j);
    a[i] = t;
  }
#pragma unroll
  for (int i = 0; i < 8; ++i) {
    short8 t;
#pragma unroll
    for (int j = 0; j < 8; ++j) t[j] = (short)(lane + i * 5 + j);
    b[i] = t;
  }
  f32x4 acc[4][8];
#pragma unroll
  for (int i = 0; i < 4; ++i)
#pragma unroll
    for (int j = 0; j < 8; ++j) acc[i][j] = (f32x4){0.f, 0.f, 0.f, 0.f};
  for (int ks = 0; ks < 8; ++ks) PSTEP(a, b)
  float s = 0.f;
#pragma unroll
  for (int i = 0; i < 4; ++i)
#pragma unroll
    for (int j = 0; j < 8; ++j) s += acc[i][j][0] + acc[i][j][1] + acc[i][j][2] + acc[i][j][3];
  asm volatile("" :: "v"(s));
}

// Probe B/C: MFMA + R7-pattern loads (16 rows x 64B per instr) from `base`.
// Launched twice: base = emb (d_in) and base = d_out. Reads [0, 4.2MB).
__global__ __launch_bounds__(256, 2) void probe_ld_mfma(const char* __restrict__ base) {
  int tid = threadIdx.x;
  int wid = tid >> 6, lane = tid & 63;
  int llo = lane & 15, lhi = lane >> 4;
  int r0 = ((blockIdx.x * 4 + wid) * 16) & 8191;
  f32x4 acc[4][8];
#pragma unroll
  for (int i = 0; i < 4; ++i)
#pragma unroll
    for (int j = 0; j < 8; ++j) acc[i][j] = (f32x4){0.f, 0.f, 0.f, 0.f};
  for (int ks = 0; ks < 8; ++ks) {
    short8 a[4], b[8];
#pragma unroll
    for (int i = 0; i < 4; ++i)
      a[i] = *(const short8*)(base + (size_t)((r0 + llo + 16 * i) & 8191) * 512 + lhi * 16 + ks * 64);
#pragma unroll
    for (int j = 0; j < 8; ++j)
      b[j] = *(const short8*)(base + (size_t)((r0 + 4096 + llo + 16 * j) & 8191) * 512 + lhi * 16 + ks * 64);
    PSTEP(a, b)
  }
  float s = 0.f;
#pragma unroll
  for (int i = 0; i < 4; ++i)
#pragma unroll
    for (int j = 0; j < 8; ++j) s += acc[i][j][0] + acc[i][j][1] + acc[i][j][2] + acc[i][j][3];
  asm volatile("" :: "v"(s));
}
#undef PSTEP

extern "C" void kernel_launch(void* const* d_in, const int* in_sizes, int n_in,
                              void* d_out, int out_size, void* d_ws, size_t ws_size,
                              hipStream_t stream) {
  const float* z   = (const float*)d_in[0];
  const float* emb = (const float*)d_in[1];
  float* out = (float*)d_out;

  // ws: pK1|pK2|pK3 (3 x 2 MB) | x2 | idx | lossPart  -> ~6.07 MB (<= proven 12.07 floor)
  u64* pK1 = (u64*)d_ws;
  u64* pK2 = pK1 + (size_t)NBLK * NROW;
  u64* pK3 = pK2 + (size_t)NBLK * NROW;
  float* x2g = (float*)(pK3 + (size_t)NBLK * NROW);
  int* idx = (int*)(x2g + NROW);
  float* lossPart = (float*)(idx + NROW);

  hipLaunchKernelGGL(x2_kernel, dim3(NROW / 32), dim3(256), 0, stream, z, x2g);
  hipLaunchKernelGGL(gemm_valu_top3_kernel, dim3(32 * 64), dim3(256), 0, stream,
                     z, emb, pK1, pK2, pK3);
  hipLaunchKernelGGL(merge_rerank_kernel, dim3(NROW / 256), dim3(256), 0, stream,
                     z, emb, pK1, pK2, pK3, x2g, idx, out);
  hipLaunchKernelGGL(gather_kernel, dim3(NROW / 64), dim3(256), 0, stream,
                     z, emb, idx, out, lossPart);
  hipLaunchKernelGGL(loss_kernel, dim3(1), dim3(64), 0, stream, lossPart, out);

  // diagnostics (timed but isolated; removed next round)
  hipLaunchKernelGGL(probe_mfma_only, dim3(512), dim3(256), 0, stream);
  hipLaunchKernelGGL(probe_ld_mfma, dim3(512), dim3(256), 0, stream, (const char*)emb);
  hipLaunchKernelGGL(probe_ld_mfma, dim3(512), dim3(256), 0, stream, (const char*)d_out);
}

// Round 10
// 652.273 us; speedup vs baseline: 1.3099x; 1.3099x over previous
//
#include <hip/hip_runtime.h>
#include <hip/hip_bf16.h>
#include <math.h>

#define NROW   8192      // B*H*W z-rows
#define KCODE  8192      // codebook entries
#define CD     256
#define HWSZ   1024
#define NBLK   64        // 128-code blocks for top-3 candidates (R5-proven layout)
#define MARGIN 7.5e-5f

#define QOFF   ((size_t)NROW * CD)   // 2097152: loss at QOFF, indices at QOFF+1

typedef __attribute__((ext_vector_type(8))) short short8;
typedef __attribute__((ext_vector_type(4))) float f32x4;
typedef unsigned long long u64;

// sortable key: high32 = monotone float map, low32 = code (lex tie -> low index)
__device__ __forceinline__ u64 makeKey(float v, int code) {
  unsigned u = __float_as_uint(v);
  unsigned m = (u & 0x80000000u) ? ~u : (u | 0x80000000u);
  return ((u64)m << 32) | (unsigned)code;
}
__device__ __forceinline__ float keyVal(u64 k) {
  unsigned m = (unsigned)(k >> 32);
  unsigned u = (m & 0x80000000u) ? (m ^ 0x80000000u) : ~m;
  return __uint_as_float(u);
}
__device__ __forceinline__ void ins3(u64 k, u64& t1, u64& t2, u64& t3) {
  if (k < t1) { t3 = t2; t2 = t1; t1 = k; }
  else if (k < t2) { t3 = t2; t2 = k; }
  else if (k < t3) { t3 = k; }
}

// ---------------- k1: z -> Xhi bf16 [n][c] + exact-numpy x2 (R2-proven) ----------------
__global__ __launch_bounds__(256) void splitz_x2_kernel(
    const float* __restrict__ z, unsigned short* __restrict__ Xhi,
    float* __restrict__ x2g) {
  __shared__ float xs[32 * 260];
  int tid = threadIdx.x;
  int n0 = blockIdx.x * 32;
  int b = n0 >> 10;
  int hw0 = n0 & 1023;
  const float* zb = z + (size_t)b * (CD * HWSZ) + hw0;
  {
    int r = tid & 31;
    int cbase = tid >> 5;
    for (int it = 0; it < 32; ++it) {
      int c = cbase + it * 8;
      xs[r * 260 + c] = zb[(size_t)c * HWSZ + r];
    }
  }
  __syncthreads();
  if (tid < 32) {
#pragma clang fp contract(off)
    const float* xr = &xs[tid * 260];
    float r0[8], r1[8];
#pragma unroll
    for (int j = 0; j < 8; ++j) {
      float v = xr[j];       r0[j] = v * v;
      float w = xr[128 + j]; r1[j] = w * w;
    }
    for (int i = 8; i < 128; i += 8) {
#pragma unroll
      for (int j = 0; j < 8; ++j) {
        float v = xr[i + j];       float a  = v * v; r0[j] = r0[j] + a;
        float w = xr[128 + i + j]; float b2 = w * w; r1[j] = r1[j] + b2;
      }
    }
    float lo = ((r0[0] + r0[1]) + (r0[2] + r0[3])) + ((r0[4] + r0[5]) + (r0[6] + r0[7]));
    float hi = ((r1[0] + r1[1]) + (r1[2] + r1[3])) + ((r1[4] + r1[5]) + (r1[6] + r1[7]));
    x2g[n0 + tid] = lo + hi;
  }
  for (int r = 0; r < 32; ++r) {
    float v = xs[r * 260 + tid];
    __hip_bfloat16 h = __float2bfloat16(v);
    Xhi[(size_t)(n0 + r) * CD + tid] = *(unsigned short*)&h;
  }
}

// ---------------- k2: emb -> Ehi bf16 [k][c] ----------------
__global__ __launch_bounds__(256) void splite_kernel(
    const float* __restrict__ emb, unsigned short* __restrict__ Ehi) {
  int n = blockIdx.x * 256 + threadIdx.x;
  __hip_bfloat16 h = __float2bfloat16(emb[n]);
  Ehi[n] = *(unsigned short*)&h;
}

// ---------------- k3: MFMA GEMM (direct-global, spill-free) + top-3 ----------------
// R7 pipeline resized to fit registers: 4 waves x (64 codes x 64 rows),
// acc[4][4] (64 VGPR) + 2-deep frag bufs (64 VGPR) ~ 150 total.
// __launch_bounds__(256,1): min-1-wave/EU -> VGPR cap 512, NO compiler clamp.
// (R5-R9 all silently spilled acc to scratch: VGPR_Count 68-128 vs 96-240 needed.)
__global__ __launch_bounds__(256, 1) void gemm_top3_kernel(
    const unsigned short* __restrict__ Eg,   // A [8192][256] bf16
    const unsigned short* __restrict__ Xg,   // B [8192][256] bf16
    u64* __restrict__ pK1, u64* __restrict__ pK2, u64* __restrict__ pK3) {
  __shared__ u64 redK[2][128][3];   // 6 KB (R5 layout)

  int tid = threadIdx.x;
  int bid = blockIdx.x;                         // 0..4095
  int swz = (bid & 7) * 512 + (bid >> 3);       // XCD swizzle (bijective, 4096%8==0)
  int cbx = swz & 63, rby = swz >> 6;
  int cb0 = cbx * 128;   // code tile
  int rb0 = rby * 128;   // zrow tile
  int wid = tid >> 6, lane = tid & 63;
  int llo = lane & 15, lhi = lane >> 4;
  int wr = wid & 1, wc = wid >> 1;   // wave quadrant: codes 64*wr, zrows 64*wc

  f32x4 acc[4][4];
#pragma unroll
  for (int i = 0; i < 4; ++i)
#pragma unroll
    for (int j = 0; j < 4; ++j) acc[i][j] = (f32x4){0.f, 0.f, 0.f, 0.f};

  // frag bases: A row = cb0+64*wr+16*i+llo, B row = rb0+64*wc+16*j+llo; 16B k-slice lhi*16
  const char* Ab = (const char*)Eg + ((size_t)(cb0 + 64 * wr + llo)) * 512 + lhi * 16;
  const char* Bb = (const char*)Xg + ((size_t)(rb0 + 64 * wc + llo)) * 512 + lhi * 16;

#define LA(dst, ks) { _Pragma("unroll") for (int i = 0; i < 4; ++i) \
    dst[i] = *(const short8*)(Ab + (size_t)i * 8192 + (ks) * 64); }
#define LB(dst, ks) { _Pragma("unroll") for (int j = 0; j < 4; ++j) \
    dst[j] = *(const short8*)(Bb + (size_t)j * 8192 + (ks) * 64); }
#define STEP(a, b) { _Pragma("unroll") for (int i = 0; i < 4; ++i) \
    _Pragma("unroll") for (int j = 0; j < 4; ++j) \
      acc[i][j] = __builtin_amdgcn_mfma_f32_16x16x32_bf16(a[i], b[j], acc[i][j], 0, 0, 0); }

  short8 a0[4], b0[4], a1[4], b1[4];
  LA(a0, 0) LB(b0, 0)
  LA(a1, 1) LB(b1, 1)
#pragma unroll
  for (int ks = 0; ks < 8; ks += 2) {
    STEP(a0, b0)
    if (ks + 2 < 8) { LA(a0, ks + 2) LB(b0, ks + 2) }
    STEP(a1, b1)
    if (ks + 3 < 8) { LA(a1, ks + 3) LB(b1, ks + 3) }
  }
#undef LA
#undef LB
#undef STEP

  // epilogue (R5-validated): v = -2*dot (monotone; x2 cancels per-row), top-3
  // per row over this wave's 64 codes, reduce over lhi groups (xor 16,32).
  // C/D: zrow = rb0+64*wc+16*j+llo, code = cb0+64*wr+16*i+4*lhi+r4 (m89-verified)
#pragma unroll
  for (int j = 0; j < 4; ++j) {
    u64 t1 = ~0ull, t2 = ~0ull, t3 = ~0ull;
#pragma unroll
    for (int i = 0; i < 4; ++i)
#pragma unroll
      for (int r4 = 0; r4 < 4; ++r4) {
        float v = -2.0f * acc[i][j][r4];
        int code = cb0 + 64 * wr + 16 * i + 4 * lhi + r4;
        ins3(makeKey(v, code), t1, t2, t3);
      }
#pragma unroll
    for (int off = 16; off < 64; off <<= 1) {
      u64 o1 = __shfl_xor(t1, off, 64);
      u64 o2 = __shfl_xor(t2, off, 64);
      u64 o3 = __shfl_xor(t3, off, 64);
      ins3(o1, t1, t2, t3); ins3(o2, t1, t2, t3); ins3(o3, t1, t2, t3);
    }
    if (lhi == 0) {
      int zl = 64 * wc + 16 * j + llo;
      redK[wr][zl][0] = t1; redK[wr][zl][1] = t2; redK[wr][zl][2] = t3;
    }
  }
  __syncthreads();
  if (tid < 128) {
    u64 t1 = redK[0][tid][0], t2 = redK[0][tid][1], t3 = redK[0][tid][2];
    ins3(redK[1][tid][0], t1, t2, t3);
    ins3(redK[1][tid][1], t1, t2, t3);
    ins3(redK[1][tid][2], t1, t2, t3);
    size_t o = (size_t)cbx * NROW + rb0 + tid;
    pK1[o] = t1; pK2[o] = t2; pK3[o] = t3;
  }
}

// ---------------- k4: merge blocks + exact re-rank (R2 semantics, R5-validated) ----------------
__global__ __launch_bounds__(256) void merge_rerank_kernel(
    const float* __restrict__ z, const float* __restrict__ emb,
    const u64* __restrict__ pK1, const u64* __restrict__ pK2,
    const u64* __restrict__ pK3, const float* __restrict__ x2g,
    int* __restrict__ idx, float* __restrict__ out) {
  int n = blockIdx.x * 256 + threadIdx.x;
  u64 kmin = ~0ull;
  for (int blk = 0; blk < NBLK; ++blk) {
    u64 k = pK1[(size_t)blk * NROW + n];
    if (k < kmin) kmin = k;
  }
  float vcut = keyVal(kmin) + MARGIN;
  int cand[8]; int nc = 0;
  for (int blk = 0; blk < NBLK; ++blk) {
    size_t o = (size_t)blk * NROW + n;
    u64 k1 = pK1[o], k2 = pK2[o], k3 = pK3[o];
    if (keyVal(k1) <= vcut && nc < 8) cand[nc++] = (int)(k1 & 0xffffffffu);
    if (keyVal(k2) <= vcut && nc < 8) cand[nc++] = (int)(k2 & 0xffffffffu);
    if (keyVal(k3) <= vcut && nc < 8) cand[nc++] = (int)(k3 & 0xffffffffu);
  }
  int b = n >> 10, hw = n & 1023;
  const float* zp = z + (size_t)b * (CD * HWSZ) + hw;
  float x2 = x2g[n];
  float bs = INFINITY; int bi = 0x7fffffff;
  for (int c0 = 0; c0 < nc; ++c0) {
    int k = cand[c0];
    const float* ep = emb + (size_t)k * CD;
    float acc = 0.f;
    for (int c = 0; c < CD; ++c)                 // sequential fmaf chain == R2 dot
      acc = fmaf(zp[(size_t)c * HWSZ], ep[c], acc);
    float s = fmaf(-2.f, acc, x2);               // single rounding == np grid
    if (s < bs || (s == bs && k < bi)) { bs = s; bi = k; }
  }
  idx[n] = bi;
  out[QOFF + 1 + n] = (float)bi;
}

// ---------------- k5: gather quantized + loss partials (R2-proven) ----------------
__global__ __launch_bounds__(256) void gather_kernel(
    const float* __restrict__ z, const float* __restrict__ emb,
    const int* __restrict__ idx, float* __restrict__ out,
    float* __restrict__ lossPart) {
  __shared__ int sidx[64];
  __shared__ float swsum[4];
  int tid = threadIdx.x;
  int bid = blockIdx.x;
  int n0 = bid * 64;
  if (tid < 64) sidx[tid] = idx[n0 + tid];
  __syncthreads();
  int lane = tid & 63;
  int cw = tid >> 6;
  int b = n0 >> 10;
  int hw = (n0 & 1023) + lane;
  const float* erow = emb + (size_t)sidx[lane] * CD;
  float lacc = 0.f;
  for (int ci = 0; ci < 64; ++ci) {
    int c = cw * 64 + ci;
    float q = erow[c];
    size_t o = (size_t)b * (CD * HWSZ) + (size_t)c * HWSZ + hw;
    float zv = z[o];
    out[o] = q;
    float d = q - zv;
    lacc += d * d;
  }
#pragma unroll
  for (int off = 32; off > 0; off >>= 1) lacc += __shfl_down(lacc, off, 64);
  if (lane == 0) swsum[cw] = lacc;
  __syncthreads();
  if (tid == 0) lossPart[bid] = swsum[0] + swsum[1] + swsum[2] + swsum[3];
}

__global__ void loss_kernel(const float* __restrict__ lossPart, float* __restrict__ out) {
  if (threadIdx.x == 0) {
    double s = 0.0;
    for (int i = 0; i < 128; ++i) s += (double)lossPart[i];
    out[QOFF] = (float)(s * 1.25 / (double)(NROW * CD));
  }
}

extern "C" void kernel_launch(void* const* d_in, const int* in_sizes, int n_in,
                              void* d_out, int out_size, void* d_ws, size_t ws_size,
                              hipStream_t stream) {
  const float* z   = (const float*)d_in[0];
  const float* emb = (const float*)d_in[1];
  float* out = (float*)d_out;

  // bf16 operands in d_out's 8MB quantized region (R5-R8 proven; overwritten by gather)
  unsigned short* Ehi = (unsigned short*)d_out;                       // 4 MB
  unsigned short* Xhi = (unsigned short*)d_out + (size_t)KCODE * CD;  // 4 MB

  // ws: pK1|pK2|pK3 (3 x 4 MB) | x2 | idx | lossPart -> 12.07 MB (R5-proven size)
  u64* pK1 = (u64*)d_ws;
  u64* pK2 = pK1 + (size_t)NBLK * NROW;
  u64* pK3 = pK2 + (size_t)NBLK * NROW;
  float* x2g = (float*)(pK3 + (size_t)NBLK * NROW);
  int* idx = (int*)(x2g + NROW);
  float* lossPart = (float*)(idx + NROW);

  hipLaunchKernelGGL(splitz_x2_kernel, dim3(NROW / 32), dim3(256), 0, stream, z, Xhi, x2g);
  hipLaunchKernelGGL(splite_kernel, dim3((KCODE * CD) / 256), dim3(256), 0, stream, emb, Ehi);
  hipLaunchKernelGGL(gemm_top3_kernel, dim3((KCODE / 128) * (NROW / 128)), dim3(256), 0, stream,
                     Ehi, Xhi, pK1, pK2, pK3);
  hipLaunchKernelGGL(merge_rerank_kernel, dim3(NROW / 256), dim3(256), 0, stream,
                     z, emb, pK1, pK2, pK3, x2g, idx, out);
  hipLaunchKernelGGL(gather_kernel, dim3(NROW / 64), dim3(256), 0, stream,
                     z, emb, idx, out, lossPart);
  hipLaunchKernelGGL(loss_kernel, dim3(1), dim3(64), 0, stream, lossPart, out);
}